// Round 14
// baseline (148.252 us; speedup 1.0000x reference)
//
#include <hip/hip_runtime.h>
#include <cstdint>

#define NN 40000
#define EE 640000
#define DD 128
#define HH 4
#define CC 32
#define LL 2
#define NEG_SLOPE 0.2f
#define NBLK 157     // ceil(NN/256)
#define PREPBLK 5000 // NN*DD/4/256
#define RANKBLK 2500 // EE/256

typedef __attribute__((ext_vector_type(8))) short bf16x8;
typedef __attribute__((ext_vector_type(4))) float f32x4;
typedef __attribute__((ext_vector_type(2))) float f32x2;
typedef __attribute__((ext_vector_type(4))) unsigned short u16x4;

__device__ __forceinline__ unsigned short f2bf(float f) {
    unsigned u = __float_as_uint(f);
    unsigned r = (u + 0x7FFFu + ((u >> 16) & 1)) >> 16;
    return (unsigned short)r;
}
__device__ __forceinline__ float bf2f(unsigned short u) {
    return __uint_as_float(((unsigned)u) << 16);
}

__device__ __forceinline__ void gload16(const void* g, void* l) {
    __builtin_amdgcn_global_load_lds(
        (const __attribute__((address_space(1))) unsigned*)g,
        (__attribute__((address_space(3))) unsigned*)l, 16, 0, 0);
}

// butterfly add via DPP (pure VALU, no LDS pipe)
template<int CTRL>
__device__ __forceinline__ float dpp_badd(float v) {
    const int j = __builtin_amdgcn_mov_dpp(__float_as_int(v), CTRL, 0xF, 0xF, true);
    return v + __int_as_float(j);
}

// Fused prep+rank: blocks [0,PREPBLK) do x fp32->bf16 + W pack (both layers);
// blocks [PREPBLK, PREPBLK+RANKBLK) do rank[e] = atomicAdd(&deg[dst[e]],1).
// deg pre-zeroed by hipMemsetAsync. Independent paths -> overlap in one dispatch.
__global__ __launch_bounds__(256) void prep_kernel(
    const float* __restrict__ x,
    const float* __restrict__ Wl, const float* __restrict__ Wr,
    const float* __restrict__ Wres,
    unsigned short* __restrict__ xb, unsigned short* __restrict__ Wb,
    const int* __restrict__ dst, int* __restrict__ deg, int* __restrict__ rank)
{
    const int rb = (int)blockIdx.x - PREPBLK;
    if (rb >= 0) {   // rank path
        const int e = rb * 256 + threadIdx.x;
        if (e < EE) rank[e] = atomicAdd(&deg[dst[e]], 1);
        return;
    }
    const int i = blockIdx.x * 256 + threadIdx.x;
    if (i < NN * DD / 4) {
        const float4 v = ((const float4*)x)[i];
        ushort4 o;
        o.x = f2bf(v.x); o.y = f2bf(v.y); o.z = f2bf(v.z); o.w = f2bf(v.w);
        ((ushort4*)xb)[i] = o;
    }
    if (i < LL * 6 * 8192) {
        const int l = i / 49152;
        const int rem0 = i - l * 49152;
        const int nb = rem0 >> 13;
        const int rem = rem0 & 8191;
        const int q = rem >> 9;
        const int n = (rem >> 3) & 63;
        const int j = rem & 7;
        const int k = q * 8 + j;
        const int colg = (nb & 1) * 64 + n;
        const float* W = (nb < 2) ? Wl : (nb < 4) ? Wr : Wres;
        Wb[i] = f2bf(W[(size_t)l * DD * DD + k * DD + colg]);
    }
}

__global__ __launch_bounds__(256) void scan1_kernel(
    const int* __restrict__ deg, int* __restrict__ rowptr, int* __restrict__ blksum)
{
    __shared__ int s[256];
    const int i = blockIdx.x * 256 + threadIdx.x;
    const int v = (i < NN) ? deg[i] : 0;
    s[threadIdx.x] = v;
    __syncthreads();
    for (int off = 1; off < 256; off <<= 1) {
        const int t = (threadIdx.x >= off) ? s[threadIdx.x - off] : 0;
        __syncthreads();
        s[threadIdx.x] += t;
        __syncthreads();
    }
    if (i < NN) rowptr[i] = s[threadIdx.x] - v;
    if (threadIdx.x == 255) blksum[blockIdx.x] = s[255];
}

// fused scan2+scan3: every block redundantly scans the 157 block sums (cheap),
// then applies its offset and writes rowptr
__global__ __launch_bounds__(256) void scan23_kernel(
    int* __restrict__ rowptr, const int* __restrict__ blksum)
{
    __shared__ int s[256];
    const int v = (threadIdx.x < NBLK) ? blksum[threadIdx.x] : 0;
    s[threadIdx.x] = v;
    __syncthreads();
    for (int off = 1; off < 256; off <<= 1) {
        const int t = (threadIdx.x >= off) ? s[threadIdx.x - off] : 0;
        __syncthreads();
        s[threadIdx.x] += t;
        __syncthreads();
    }
    const int boff = s[blockIdx.x] - blksum[blockIdx.x];
    const int i = blockIdx.x * 256 + threadIdx.x;
    if (i < NN) rowptr[i] = rowptr[i] + boff;
    if (i == 0) rowptr[NN] = EE;
}

// MFMA GEMM (+ optional fused CSR-fill blocks): blocks [0,625) compute
// [40000][384] = x_bf16 @ [Wl|Wr|Wres] + bias -> xl/xr/res (bf16);
// blocks [625, 625+fillBlocks) scatter colb[rowptr[dst]+rank] = src<<8.
__global__ __launch_bounds__(256) void gemm_mfma_kernel(
    const unsigned short* __restrict__ xb, const unsigned short* __restrict__ Wb,
    const float* __restrict__ bl, const float* __restrict__ br,
    const float* __restrict__ bias,
    unsigned short* __restrict__ xlb, unsigned short* __restrict__ xrb,
    unsigned short* __restrict__ resb,
    const int* __restrict__ src, const int* __restrict__ dst,
    const int* __restrict__ rank, const int* __restrict__ rowptr,
    int* __restrict__ colb)
{
    __shared__ __align__(16) unsigned short lds[16384];  // A:0..8191, B:8192..16383
    const int fb = (int)blockIdx.x - 625;
    if (fb >= 0) {       // CSR fill path (no atomics: rank precomputed)
        const int e = fb * 256 + threadIdx.x;
        if (e < EE) colb[rowptr[dst[e]] + rank[e]] = src[e] << 8;
        return;
    }
    const int lane = threadIdx.x & 63;
    const int wv = threadIdx.x >> 6;
    const int row0 = blockIdx.x << 6;

#pragma unroll
    for (int j = 0; j < 4; ++j) {
        const int q = j * 4 + wv;
        gload16(xb + (size_t)(row0 + lane) * DD + q * 8, &lds[q * 512]);
    }

    const int wm = wv >> 1, wn = wv & 1;
    const int h = lane >> 4, r = lane & 15;

    for (int t = 0; t < 6; ++t) {
        __syncthreads();
#pragma unroll
        for (int j = 0; j < 4; ++j) {
            const int q = j * 4 + wv;
            gload16(Wb + (size_t)t * 8192 + q * 512 + lane * 8, &lds[8192 + q * 512]);
        }
        __syncthreads();

        f32x4 acc[2][2] = {{{0.f,0.f,0.f,0.f},{0.f,0.f,0.f,0.f}},
                           {{0.f,0.f,0.f,0.f},{0.f,0.f,0.f,0.f}}};
#pragma unroll
        for (int s = 0; s < 4; ++s) {
            const int base = (s * 4 + h) * 64;
            const bf16x8 a0 = *(const bf16x8*)&lds[(base + wm * 32 + r) * 8];
            const bf16x8 a1 = *(const bf16x8*)&lds[(base + wm * 32 + 16 + r) * 8];
            const bf16x8 b0 = *(const bf16x8*)&lds[8192 + (base + wn * 32 + r) * 8];
            const bf16x8 b1 = *(const bf16x8*)&lds[8192 + (base + wn * 32 + 16 + r) * 8];
            acc[0][0] = __builtin_amdgcn_mfma_f32_16x16x32_bf16(a0, b0, acc[0][0], 0, 0, 0);
            acc[0][1] = __builtin_amdgcn_mfma_f32_16x16x32_bf16(a0, b1, acc[0][1], 0, 0, 0);
            acc[1][0] = __builtin_amdgcn_mfma_f32_16x16x32_bf16(a1, b0, acc[1][0], 0, 0, 0);
            acc[1][1] = __builtin_amdgcn_mfma_f32_16x16x32_bf16(a1, b1, acc[1][1], 0, 0, 0);
        }

        unsigned short* const outp = (t < 2) ? xlb : (t < 4) ? xrb : resb;
        const float* const bp = (t < 2) ? bl : (t < 4) ? br : bias;
        const int c0 = (t & 1) * 64 + wn * 32;
#pragma unroll
        for (int ni = 0; ni < 2; ++ni) {
            const int col = c0 + ni * 16 + r;
            const float bv = bp[col];
#pragma unroll
            for (int mi = 0; mi < 2; ++mi) {
                const int rw = row0 + wm * 32 + mi * 16 + h * 4;
#pragma unroll
                for (int v = 0; v < 4; ++v)
                    outp[(size_t)(rw + v) * DD + col] = f2bf(acc[mi][ni][v] + bv);
            }
        }
    }
}

// ------------- fused score + softmax (no-max, fp32-safe) + agg + ELU -------
// ONE WAVE PER BLOCK (64 threads), node = blockIdx.x. lane owns 4 channels
// (hl = lane&31); wave-halves process disjoint edges; 8 edges per chunk.
// Output stores are non-temporal (never usefully re-read through L2; avoids
// evicting the 10.2MB xlb gather working set).
__global__ __launch_bounds__(64) void gather_kernel(
    const unsigned short* __restrict__ xlb, const unsigned short* __restrict__ xrb,
    const unsigned short* __restrict__ resb,
    const int* __restrict__ rowptr, const int* __restrict__ colb,
    const float* __restrict__ att,
    float* __restrict__ outf, unsigned short* __restrict__ outb)
{
    const int node = blockIdx.x;
    const int lane = threadIdx.x;
    const int halfid = lane >> 5;
    const int hl = lane & 31;          // owns channels [hl*4, hl*4+4)

    const uint2 xu = *(const uint2*)(xrb + (size_t)node * DD + hl * 4);
    const f32x2 xr01 = {__uint_as_float(xu.x << 16), __uint_as_float(xu.x & 0xFFFF0000u)};
    const f32x2 xr23 = {__uint_as_float(xu.y << 16), __uint_as_float(xu.y & 0xFFFF0000u)};
    const float4 attv = ((const float4*)att)[hl];
    const f32x2 at6_01 = {0.6f * attv.x, 0.6f * attv.y};
    const f32x2 at6_23 = {0.6f * attv.z, 0.6f * attv.w};
    const f32x2 at4_01 = {0.4f * attv.x, 0.4f * attv.y};
    const f32x2 at4_23 = {0.4f * attv.z, 0.4f * attv.w};
    const char* const xbase = (const char*)xlb;

    float d = 0.f;
    f32x2 acc01 = {0.f, 0.f}, acc23 = {0.f, 0.f};
    const int beg = rowptr[node], end = rowptr[node + 1];

    int p = beg;

#define CHUNK_BODY(GUARDED)                                                    \
    {                                                                          \
        f32x2 xv01[4], xv23[4]; float al[4]; int vl[4];                        \
        _Pragma("unroll")                                                      \
        for (int i = 0; i < 4; ++i) {                                          \
            const int q = p + 2 * i + halfid;                                  \
            vl[i] = GUARDED ? (q < end) : 1;                                   \
            const int off = colb[vl[i] ? q : beg];                             \
            const uint2 u = *(const uint2*)(xbase + off + hl * 8);             \
            xv01[i] = (f32x2){__uint_as_float(u.x << 16),                      \
                              __uint_as_float(u.x & 0xFFFF0000u)};             \
            xv23[i] = (f32x2){__uint_as_float(u.y << 16),                      \
                              __uint_as_float(u.y & 0xFFFF0000u)};             \
        }                                                                      \
        _Pragma("unroll")                                                      \
        for (int i = 0; i < 4; ++i) {                                          \
            const f32x2 z01 = xv01[i] + xr01;                                  \
            const f32x2 z23 = xv23[i] + xr23;                                  \
            const f32x2 za01 = __builtin_elementwise_abs(z01);                 \
            const f32x2 za23 = __builtin_elementwise_abs(z23);                 \
            f32x2 s2 = z01 * at6_01;                                           \
            s2 += za01 * at4_01;                                               \
            s2 += z23 * at6_23;                                                \
            s2 += za23 * at4_23;                                               \
            al[i] = s2.x + s2.y;                                               \
        }                                                                      \
        _Pragma("unroll")                                                      \
        for (int i = 0; i < 4; ++i) {                                          \
            al[i] = dpp_badd<0xB1>(al[i]);   /* xor 1 (quad_perm 1,0,3,2) */   \
            al[i] = dpp_badd<0x4E>(al[i]);   /* xor 2 (quad_perm 2,3,0,1) */   \
            al[i] = dpp_badd<0x141>(al[i]);  /* xor 4 (row_half_mirror)   */   \
        }                                                                      \
        _Pragma("unroll")                                                      \
        for (int i = 0; i < 4; ++i) {                                          \
            float w = __expf(al[i]);                                           \
            if (GUARDED) w = vl[i] ? w : 0.f;                                  \
            const f32x2 w2 = {w, w};                                           \
            d += w;                                                            \
            acc01 += w2 * xv01[i];                                             \
            acc23 += w2 * xv23[i];                                             \
        }                                                                      \
    }

    for (; p + 8 <= end; p += 8) CHUNK_BODY(0)
    if (p < end) CHUNK_BODY(1)
#undef CHUNK_BODY

    // combine the two halves (disjoint edge subsets, same channels)
    d += __shfl_xor(d, 32);
    acc01.x += __shfl_xor(acc01.x, 32); acc01.y += __shfl_xor(acc01.y, 32);
    acc23.x += __shfl_xor(acc23.x, 32); acc23.y += __shfl_xor(acc23.y, 32);

    if (halfid == 0) {
        const float inv = 1.f / (d + 1e-16f);
        const ushort4 ru = ((const ushort4*)(resb + (size_t)node * DD))[hl];
        float o0 = acc01.x * inv + bf2f(ru.x);
        float o1 = acc01.y * inv + bf2f(ru.y);
        float o2 = acc23.x * inv + bf2f(ru.z);
        float o3 = acc23.y * inv + bf2f(ru.w);
        o0 = (o0 > 0.f) ? o0 : expm1f(o0);
        o1 = (o1 > 0.f) ? o1 : expm1f(o1);
        o2 = (o2 > 0.f) ? o2 : expm1f(o2);
        o3 = (o3 > 0.f) ? o3 : expm1f(o3);
        if (outf) {
            const f32x4 ov = {o0, o1, o2, o3};
            __builtin_nontemporal_store(ov, (f32x4*)(outf + (size_t)node * DD) + hl);
        }
        if (outb) {
            const u16x4 ob = {f2bf(o0), f2bf(o1), f2bf(o2), f2bf(o3)};
            __builtin_nontemporal_store(ob, (u16x4*)(outb + (size_t)node * DD) + hl);
        }
    }
}

extern "C" void kernel_launch(void* const* d_in, const int* in_sizes, int n_in,
                              void* d_out, int out_size, void* d_ws, size_t ws_size,
                              hipStream_t stream)
{
    const float* x0   = (const float*)d_in[0];
    const int*   ei   = (const int*)  d_in[1];
    const float* Wl   = (const float*)d_in[2];
    const float* bl   = (const float*)d_in[3];
    const float* Wr   = (const float*)d_in[4];
    const float* br   = (const float*)d_in[5];
    const float* att  = (const float*)d_in[6];
    const float* Wres = (const float*)d_in[7];
    const float* bias = (const float*)d_in[8];
    const int* src = ei;
    const int* dst = ei + EE;

    float* p = (float*)d_ws;
    unsigned short* xlb  = (unsigned short*)p; p += (size_t)NN * DD / 2;
    unsigned short* xrb  = (unsigned short*)p; p += (size_t)NN * DD / 2;
    unsigned short* resb = (unsigned short*)p; p += (size_t)NN * DD / 2;
    unsigned short* xb0  = (unsigned short*)p; p += (size_t)NN * DD / 2;
    unsigned short* xb1  = (unsigned short*)p; p += (size_t)NN * DD / 2;
    unsigned short* Wb   = (unsigned short*)p; p += LL * 6 * 8192 / 2;
    int* rowptr = (int*)p; p += NN + 1;
    int* deg    = (int*)p; p += NN;
    int* rank   = (int*)p; p += EE;
    int* blksum = (int*)p; p += NBLK;
    int* colb   = (int*)p; p += EE;

    (void)hipMemsetAsync(deg, 0, NN * sizeof(int), stream);
    // prep (cvt + W pack) + rank fused; then scans
    prep_kernel<<<PREPBLK + RANKBLK, 256, 0, stream>>>(
        x0, Wl, Wr, Wres, xb0, Wb, dst, deg, rank);
    scan1_kernel<<<NBLK, 256, 0, stream>>>(deg, rowptr, blksum);
    scan23_kernel<<<NBLK, 256, 0, stream>>>(rowptr, blksum);

    for (int l = 0; l < LL; ++l) {
        const unsigned short* xin = (l == 0) ? xb0 : xb1;
        const int fillBlocks = (l == 0) ? (EE + 255) / 256 : 0;  // fill fused w/ gemm1
        gemm_mfma_kernel<<<625 + fillBlocks, 256, 0, stream>>>(
            xin, Wb + (size_t)l * 6 * 8192, bl + l * DD, br + l * DD, bias + l * DD,
            xlb, xrb, resb, src, dst, rank, rowptr, colb);
        gather_kernel<<<NN, 64, 0, stream>>>(
            xlb, xrb, resb, rowptr, colb, att + (size_t)l * HH * CC,
            (l == LL - 1) ? (float*)d_out : nullptr,
            (l == 0) ? xb1 : nullptr);
    }
}

// Round 15
// 140.318 us; speedup vs baseline: 1.0565x; 1.0565x over previous
//
#include <hip/hip_runtime.h>
#include <cstdint>

#define NN 40000
#define EE 640000
#define DD 128
#define HH 4
#define CC 32
#define LL 2
#define NEG_SLOPE 0.2f
#define NBLK 157   // ceil(NN/256)

typedef __attribute__((ext_vector_type(8))) short bf16x8;
typedef __attribute__((ext_vector_type(4))) float f32x4;
typedef __attribute__((ext_vector_type(2))) float f32x2;

__device__ __forceinline__ unsigned short f2bf(float f) {
    unsigned u = __float_as_uint(f);
    unsigned r = (u + 0x7FFFu + ((u >> 16) & 1)) >> 16;
    return (unsigned short)r;
}
__device__ __forceinline__ float bf2f(unsigned short u) {
    return __uint_as_float(((unsigned)u) << 16);
}

__device__ __forceinline__ void gload16(const void* g, void* l) {
    __builtin_amdgcn_global_load_lds(
        (const __attribute__((address_space(1))) unsigned*)g,
        (__attribute__((address_space(3))) unsigned*)l, 16, 0, 0);
}

// butterfly add via DPP (pure VALU, no LDS pipe)
template<int CTRL>
__device__ __forceinline__ float dpp_badd(float v) {
    const int j = __builtin_amdgcn_mov_dpp(__float_as_int(v), CTRL, 0xF, 0xF, true);
    return v + __int_as_float(j);
}

// Fused prep: x fp32->bf16 ; W pack (both layers) ; deg zero (in-kernel — the
// runtime fillBuffer path for small memsets measured ~43us, R13 regression).
__global__ __launch_bounds__(256) void prep_kernel(
    const float* __restrict__ x,
    const float* __restrict__ Wl, const float* __restrict__ Wr,
    const float* __restrict__ Wres,
    unsigned short* __restrict__ xb, unsigned short* __restrict__ Wb,
    int* __restrict__ deg)
{
    const int i = blockIdx.x * 256 + threadIdx.x;
    if (i < NN * DD / 4) {
        const float4 v = ((const float4*)x)[i];
        ushort4 o;
        o.x = f2bf(v.x); o.y = f2bf(v.y); o.z = f2bf(v.z); o.w = f2bf(v.w);
        ((ushort4*)xb)[i] = o;
    }
    if (i < LL * 6 * 8192) {
        const int l = i / 49152;
        const int rem0 = i - l * 49152;
        const int nb = rem0 >> 13;
        const int rem = rem0 & 8191;
        const int q = rem >> 9;
        const int n = (rem >> 3) & 63;
        const int j = rem & 7;
        const int k = q * 8 + j;
        const int colg = (nb & 1) * 64 + n;
        const float* W = (nb < 2) ? Wl : (nb < 4) ? Wr : Wres;
        Wb[i] = f2bf(W[(size_t)l * DD * DD + k * DD + colg]);
    }
    if (i < NN) deg[i] = 0;
}

// rank[e] = position of edge e within its destination's row (also builds deg)
__global__ __launch_bounds__(256) void rank_kernel(
    const int* __restrict__ dst, int* __restrict__ deg, int* __restrict__ rank)
{
    const int e = blockIdx.x * 256 + threadIdx.x;
    if (e < EE) rank[e] = atomicAdd(&deg[dst[e]], 1);
}

__global__ __launch_bounds__(256) void scan1_kernel(
    const int* __restrict__ deg, int* __restrict__ rowptr, int* __restrict__ blksum)
{
    __shared__ int s[256];
    const int i = blockIdx.x * 256 + threadIdx.x;
    const int v = (i < NN) ? deg[i] : 0;
    s[threadIdx.x] = v;
    __syncthreads();
    for (int off = 1; off < 256; off <<= 1) {
        const int t = (threadIdx.x >= off) ? s[threadIdx.x - off] : 0;
        __syncthreads();
        s[threadIdx.x] += t;
        __syncthreads();
    }
    if (i < NN) rowptr[i] = s[threadIdx.x] - v;
    if (threadIdx.x == 255) blksum[blockIdx.x] = s[255];
}

// fused scan2+scan3: every block redundantly scans the 157 block sums (cheap),
// then applies its offset and writes rowptr
__global__ __launch_bounds__(256) void scan23_kernel(
    int* __restrict__ rowptr, const int* __restrict__ blksum)
{
    __shared__ int s[256];
    const int v = (threadIdx.x < NBLK) ? blksum[threadIdx.x] : 0;
    s[threadIdx.x] = v;
    __syncthreads();
    for (int off = 1; off < 256; off <<= 1) {
        const int t = (threadIdx.x >= off) ? s[threadIdx.x - off] : 0;
        __syncthreads();
        s[threadIdx.x] += t;
        __syncthreads();
    }
    const int boff = s[blockIdx.x] - blksum[blockIdx.x];
    const int i = blockIdx.x * 256 + threadIdx.x;
    if (i < NN) rowptr[i] = rowptr[i] + boff;
    if (i == 0) rowptr[NN] = EE;
}

// MFMA GEMM (+ optional fused CSR-fill blocks): blocks [0,625) compute
// [40000][384] = x_bf16 @ [Wl|Wr|Wres] + bias -> xl/xr/res (bf16);
// blocks [625, 625+fillBlocks) scatter colb[rowptr[dst]+rank] = src<<8.
__global__ __launch_bounds__(256) void gemm_mfma_kernel(
    const unsigned short* __restrict__ xb, const unsigned short* __restrict__ Wb,
    const float* __restrict__ bl, const float* __restrict__ br,
    const float* __restrict__ bias,
    unsigned short* __restrict__ xlb, unsigned short* __restrict__ xrb,
    unsigned short* __restrict__ resb,
    const int* __restrict__ src, const int* __restrict__ dst,
    const int* __restrict__ rank, const int* __restrict__ rowptr,
    int* __restrict__ colb)
{
    __shared__ __align__(16) unsigned short lds[16384];  // A:0..8191, B:8192..16383
    const int fb = (int)blockIdx.x - 625;
    if (fb >= 0) {       // CSR fill path (no atomics: rank precomputed)
        const int e = fb * 256 + threadIdx.x;
        if (e < EE) colb[rowptr[dst[e]] + rank[e]] = src[e] << 8;
        return;
    }
    const int lane = threadIdx.x & 63;
    const int wv = threadIdx.x >> 6;
    const int row0 = blockIdx.x << 6;

#pragma unroll
    for (int j = 0; j < 4; ++j) {
        const int q = j * 4 + wv;
        gload16(xb + (size_t)(row0 + lane) * DD + q * 8, &lds[q * 512]);
    }

    const int wm = wv >> 1, wn = wv & 1;
    const int h = lane >> 4, r = lane & 15;

    for (int t = 0; t < 6; ++t) {
        __syncthreads();
#pragma unroll
        for (int j = 0; j < 4; ++j) {
            const int q = j * 4 + wv;
            gload16(Wb + (size_t)t * 8192 + q * 512 + lane * 8, &lds[8192 + q * 512]);
        }
        __syncthreads();

        f32x4 acc[2][2] = {{{0.f,0.f,0.f,0.f},{0.f,0.f,0.f,0.f}},
                           {{0.f,0.f,0.f,0.f},{0.f,0.f,0.f,0.f}}};
#pragma unroll
        for (int s = 0; s < 4; ++s) {
            const int base = (s * 4 + h) * 64;
            const bf16x8 a0 = *(const bf16x8*)&lds[(base + wm * 32 + r) * 8];
            const bf16x8 a1 = *(const bf16x8*)&lds[(base + wm * 32 + 16 + r) * 8];
            const bf16x8 b0 = *(const bf16x8*)&lds[8192 + (base + wn * 32 + r) * 8];
            const bf16x8 b1 = *(const bf16x8*)&lds[8192 + (base + wn * 32 + 16 + r) * 8];
            acc[0][0] = __builtin_amdgcn_mfma_f32_16x16x32_bf16(a0, b0, acc[0][0], 0, 0, 0);
            acc[0][1] = __builtin_amdgcn_mfma_f32_16x16x32_bf16(a0, b1, acc[0][1], 0, 0, 0);
            acc[1][0] = __builtin_amdgcn_mfma_f32_16x16x32_bf16(a1, b0, acc[1][0], 0, 0, 0);
            acc[1][1] = __builtin_amdgcn_mfma_f32_16x16x32_bf16(a1, b1, acc[1][1], 0, 0, 0);
        }

        unsigned short* const outp = (t < 2) ? xlb : (t < 4) ? xrb : resb;
        const float* const bp = (t < 2) ? bl : (t < 4) ? br : bias;
        const int c0 = (t & 1) * 64 + wn * 32;
#pragma unroll
        for (int ni = 0; ni < 2; ++ni) {
            const int col = c0 + ni * 16 + r;
            const float bv = bp[col];
#pragma unroll
            for (int mi = 0; mi < 2; ++mi) {
                const int rw = row0 + wm * 32 + mi * 16 + h * 4;
#pragma unroll
                for (int v = 0; v < 4; ++v)
                    outp[(size_t)(rw + v) * DD + col] = f2bf(acc[mi][ni][v] + bv);
            }
        }
    }
}

// ------------- fused score + softmax (no-max, fp32-safe) + agg + ELU -------
// ONE WAVE PER BLOCK (64 threads), node = blockIdx.x. lane owns 4 channels
// (hl = lane&31); wave-halves process disjoint edges; 8 edges per chunk.
// outf (d_out, never re-read) uses NT stores; outb (xb1, re-read by gemm2)
// uses normal stores to stay L2-resident.
__global__ __launch_bounds__(64) void gather_kernel(
    const unsigned short* __restrict__ xlb, const unsigned short* __restrict__ xrb,
    const unsigned short* __restrict__ resb,
    const int* __restrict__ rowptr, const int* __restrict__ colb,
    const float* __restrict__ att,
    float* __restrict__ outf, unsigned short* __restrict__ outb)
{
    const int node = blockIdx.x;
    const int lane = threadIdx.x;
    const int halfid = lane >> 5;
    const int hl = lane & 31;          // owns channels [hl*4, hl*4+4)

    const uint2 xu = *(const uint2*)(xrb + (size_t)node * DD + hl * 4);
    const f32x2 xr01 = {__uint_as_float(xu.x << 16), __uint_as_float(xu.x & 0xFFFF0000u)};
    const f32x2 xr23 = {__uint_as_float(xu.y << 16), __uint_as_float(xu.y & 0xFFFF0000u)};
    const float4 attv = ((const float4*)att)[hl];
    const f32x2 at6_01 = {0.6f * attv.x, 0.6f * attv.y};
    const f32x2 at6_23 = {0.6f * attv.z, 0.6f * attv.w};
    const f32x2 at4_01 = {0.4f * attv.x, 0.4f * attv.y};
    const f32x2 at4_23 = {0.4f * attv.z, 0.4f * attv.w};
    const char* const xbase = (const char*)xlb;

    float d = 0.f;
    f32x2 acc01 = {0.f, 0.f}, acc23 = {0.f, 0.f};
    const int beg = rowptr[node], end = rowptr[node + 1];

    int p = beg;

#define CHUNK_BODY(GUARDED)                                                    \
    {                                                                          \
        f32x2 xv01[4], xv23[4]; float al[4]; int vl[4];                        \
        _Pragma("unroll")                                                      \
        for (int i = 0; i < 4; ++i) {                                          \
            const int q = p + 2 * i + halfid;                                  \
            vl[i] = GUARDED ? (q < end) : 1;                                   \
            const int off = colb[vl[i] ? q : beg];                             \
            const uint2 u = *(const uint2*)(xbase + off + hl * 8);             \
            xv01[i] = (f32x2){__uint_as_float(u.x << 16),                      \
                              __uint_as_float(u.x & 0xFFFF0000u)};             \
            xv23[i] = (f32x2){__uint_as_float(u.y << 16),                      \
                              __uint_as_float(u.y & 0xFFFF0000u)};             \
        }                                                                      \
        _Pragma("unroll")                                                      \
        for (int i = 0; i < 4; ++i) {                                          \
            const f32x2 z01 = xv01[i] + xr01;                                  \
            const f32x2 z23 = xv23[i] + xr23;                                  \
            const f32x2 za01 = __builtin_elementwise_abs(z01);                 \
            const f32x2 za23 = __builtin_elementwise_abs(z23);                 \
            f32x2 s2 = z01 * at6_01;                                           \
            s2 += za01 * at4_01;                                               \
            s2 += z23 * at6_23;                                                \
            s2 += za23 * at4_23;                                               \
            al[i] = s2.x + s2.y;                                               \
        }                                                                      \
        _Pragma("unroll")                                                      \
        for (int i = 0; i < 4; ++i) {                                          \
            al[i] = dpp_badd<0xB1>(al[i]);   /* xor 1 (quad_perm 1,0,3,2) */   \
            al[i] = dpp_badd<0x4E>(al[i]);   /* xor 2 (quad_perm 2,3,0,1) */   \
            al[i] = dpp_badd<0x141>(al[i]);  /* xor 4 (row_half_mirror)   */   \
        }                                                                      \
        _Pragma("unroll")                                                      \
        for (int i = 0; i < 4; ++i) {                                          \
            float w = __expf(al[i]);                                           \
            if (GUARDED) w = vl[i] ? w : 0.f;                                  \
            const f32x2 w2 = {w, w};                                           \
            d += w;                                                            \
            acc01 += w2 * xv01[i];                                             \
            acc23 += w2 * xv23[i];                                             \
        }                                                                      \
    }

    for (; p + 8 <= end; p += 8) CHUNK_BODY(0)
    if (p < end) CHUNK_BODY(1)
#undef CHUNK_BODY

    // combine the two halves (disjoint edge subsets, same channels)
    d += __shfl_xor(d, 32);
    acc01.x += __shfl_xor(acc01.x, 32); acc01.y += __shfl_xor(acc01.y, 32);
    acc23.x += __shfl_xor(acc23.x, 32); acc23.y += __shfl_xor(acc23.y, 32);

    if (halfid == 0) {
        const float inv = 1.f / (d + 1e-16f);
        const ushort4 ru = ((const ushort4*)(resb + (size_t)node * DD))[hl];
        float o0 = acc01.x * inv + bf2f(ru.x);
        float o1 = acc01.y * inv + bf2f(ru.y);
        float o2 = acc23.x * inv + bf2f(ru.z);
        float o3 = acc23.y * inv + bf2f(ru.w);
        o0 = (o0 > 0.f) ? o0 : expm1f(o0);
        o1 = (o1 > 0.f) ? o1 : expm1f(o1);
        o2 = (o2 > 0.f) ? o2 : expm1f(o2);
        o3 = (o3 > 0.f) ? o3 : expm1f(o3);
        if (outf) {
            const f32x4 ov = {o0, o1, o2, o3};
            __builtin_nontemporal_store(ov, (f32x4*)(outf + (size_t)node * DD) + hl);
        }
        if (outb) {
            ushort4 ob;
            ob.x = f2bf(o0); ob.y = f2bf(o1); ob.z = f2bf(o2); ob.w = f2bf(o3);
            ((ushort4*)(outb + (size_t)node * DD))[hl] = ob;
        }
    }
}

extern "C" void kernel_launch(void* const* d_in, const int* in_sizes, int n_in,
                              void* d_out, int out_size, void* d_ws, size_t ws_size,
                              hipStream_t stream)
{
    const float* x0   = (const float*)d_in[0];
    const int*   ei   = (const int*)  d_in[1];
    const float* Wl   = (const float*)d_in[2];
    const float* bl   = (const float*)d_in[3];
    const float* Wr   = (const float*)d_in[4];
    const float* br   = (const float*)d_in[5];
    const float* att  = (const float*)d_in[6];
    const float* Wres = (const float*)d_in[7];
    const float* bias = (const float*)d_in[8];
    const int* src = ei;
    const int* dst = ei + EE;

    float* p = (float*)d_ws;
    unsigned short* xlb  = (unsigned short*)p; p += (size_t)NN * DD / 2;
    unsigned short* xrb  = (unsigned short*)p; p += (size_t)NN * DD / 2;
    unsigned short* resb = (unsigned short*)p; p += (size_t)NN * DD / 2;
    unsigned short* xb0  = (unsigned short*)p; p += (size_t)NN * DD / 2;
    unsigned short* xb1  = (unsigned short*)p; p += (size_t)NN * DD / 2;
    unsigned short* Wb   = (unsigned short*)p; p += LL * 6 * 8192 / 2;
    int* rowptr = (int*)p; p += NN + 1;
    int* deg    = (int*)p; p += NN;
    int* rank   = (int*)p; p += EE;
    int* blksum = (int*)p; p += NBLK;
    int* colb   = (int*)p; p += EE;

    // prep (cvt + W pack + deg zero) -> rank (hist w/ stored rank) -> scans
    prep_kernel<<<(NN * DD / 4 + 255) / 256, 256, 0, stream>>>(
        x0, Wl, Wr, Wres, xb0, Wb, deg);
    rank_kernel<<<(EE + 255) / 256, 256, 0, stream>>>(dst, deg, rank);
    scan1_kernel<<<NBLK, 256, 0, stream>>>(deg, rowptr, blksum);
    scan23_kernel<<<NBLK, 256, 0, stream>>>(rowptr, blksum);

    for (int l = 0; l < LL; ++l) {
        const unsigned short* xin = (l == 0) ? xb0 : xb1;
        const int fillBlocks = (l == 0) ? (EE + 255) / 256 : 0;  // fill fused w/ gemm1
        gemm_mfma_kernel<<<625 + fillBlocks, 256, 0, stream>>>(
            xin, Wb + (size_t)l * 6 * 8192, bl + l * DD, br + l * DD, bias + l * DD,
            xlb, xrb, resb, src, dst, rank, rowptr, colb);
        gather_kernel<<<NN, 64, 0, stream>>>(
            xlb, xrb, resb, rowptr, colb, att + (size_t)l * HH * CC,
            (l == LL - 1) ? (float*)d_out : nullptr,
            (l == 0) ? xb1 : nullptr);
    }
}